// Round 5
// baseline (353.952 us; speedup 1.0000x reference)
//
#include <hip/hip_runtime.h>
#include <hip/hip_bf16.h>

// CausalSelfAttention: x[4,2048,1024] -> qkv proj -> 16-head causal attn -> out proj
// Pipeline: cvt(fp32->bf16) x3 -> gemm_bt<QKV> -> attn (paired waveflash) -> gemm_bt<OUT>

#define B_ 4
#define T_ 2048
#define C_ 1024
#define H_ 16
#define D_ 64
#define M_ (B_*T_)   // 8192 tokens

typedef __attribute__((ext_vector_type(8))) short short8;
typedef __attribute__((ext_vector_type(4))) float f32x4;

static __device__ __forceinline__ ushort f2bf(float f) {
  __hip_bfloat16 b = __float2bfloat16(f);
  ushort u; __builtin_memcpy(&u, &b, 2); return u;
}

static __device__ __forceinline__ void ld16(const void* g, void* l) {
  __builtin_amdgcn_global_load_lds((const __attribute__((address_space(1))) void*)g,
                                   (__attribute__((address_space(3))) void*)l, 16, 0, 0);
}

static __device__ __forceinline__ f32x4 mfma16(short8 a, short8 b, f32x4 c) {
  return __builtin_amdgcn_mfma_f32_16x16x32_bf16(a, b, c, 0, 0, 0);
}

// ---------------- fp32 -> bf16 convert ----------------
__global__ void cvt_bf16(const float* __restrict__ in, ushort* __restrict__ out, int n4) {
  int i = blockIdx.x * blockDim.x + threadIdx.x;
  int st = gridDim.x * blockDim.x;
  for (; i < n4; i += st) {
    float4 v = ((const float4*)in)[i];
    ushort4 o;
    o.x = f2bf(v.x); o.y = f2bf(v.y); o.z = f2bf(v.z); o.w = f2bf(v.w);
    ((ushort4*)out)[i] = o;
  }
}

// ---------------- C = A @ B^T + bias (both A,B K-major bf16) ----------------
// MODE 0: QKV projection -> scatter to q[B,H,T,D], k[B,H,T,D], vt[B,H,D,T] (bf16)
// MODE 1: out projection -> fp32 d_out
template<int MODE>
__global__ __launch_bounds__(256) void gemm_bt(
    const ushort* __restrict__ A, const ushort* __restrict__ Bm,
    const float* __restrict__ bias, int K,
    ushort* __restrict__ q, ushort* __restrict__ kk, ushort* __restrict__ vt,
    float* __restrict__ outF)
{
  __shared__ ushort Al[128*32];
  __shared__ ushort Bl[128*32];
  const int tid = threadIdx.x;
  const int lane = tid & 63;
  const int w = tid >> 6;
  const int wr = w >> 1, wc = w & 1;
  const int l15 = lane & 15, lhi = lane >> 4;
  const long i0 = (long)blockIdx.y * 128;
  const long j0 = (long)blockIdx.x * 128;

  f32x4 acc[4][4] = {};

  for (int k0 = 0; k0 < K; k0 += 32) {
    __syncthreads();
    {
      int c = tid;
      ld16((const char*)A  + ((i0 + (c >> 2)) * K + k0 + (c & 3) * 8) * 2, (char*)Al + c * 16);
      ld16((const char*)Bm + ((j0 + (c >> 2)) * K + k0 + (c & 3) * 8) * 2, (char*)Bl + c * 16);
      c = tid + 256;
      ld16((const char*)A  + ((i0 + (c >> 2)) * K + k0 + (c & 3) * 8) * 2, (char*)Al + c * 16);
      ld16((const char*)Bm + ((j0 + (c >> 2)) * K + k0 + (c & 3) * 8) * 2, (char*)Bl + c * 16);
    }
    __syncthreads();
    short8 af[4], bf[4];
#pragma unroll
    for (int m = 0; m < 4; m++) af[m] = *(const short8*)&Al[(wr*64 + m*16 + l15)*32 + lhi*8];
#pragma unroll
    for (int n = 0; n < 4; n++) bf[n] = *(const short8*)&Bl[(wc*64 + n*16 + l15)*32 + lhi*8];
#pragma unroll
    for (int m = 0; m < 4; m++)
#pragma unroll
      for (int n = 0; n < 4; n++)
        acc[m][n] = mfma16(af[m], bf[n], acc[m][n]);
  }

#pragma unroll
  for (int m = 0; m < 4; m++) {
#pragma unroll
    for (int n = 0; n < 4; n++) {
#pragma unroll
      for (int r = 0; r < 4; r++) {
        long i = i0 + wr*64 + m*16 + lhi*4 + r;       // token row
        int  j = (int)j0 + wc*64 + n*16 + l15;        // output feature
        float v = acc[m][n][r] + bias[j];
        if (MODE == 0) {
          int b = (int)(i >> 11), t = (int)(i & 2047);
          int sel = j >> 10, cc = j & 1023;
          int h = cc >> 6, d = cc & 63;
          long bh = (long)b * H_ + h;
          ushort bv = f2bf(v);
          if (sel == 0)      q [(bh*T_ + t)*D_ + d] = bv;
          else if (sel == 1) kk[(bh*T_ + t)*D_ + d] = bv;
          else               vt[(bh*D_ + d)*T_ + t] = bv;   // V stored transposed
        } else {
          outF[i * C_ + j] = v;
        }
      }
    }
  }
}

// ---------------- causal flash attention, paired for balance ----------------
// 1024 blocks x 256 threads. Wave w of block handles TWO 16-row q-groups from
// opposite ends of the sequence: a = rows [16j,16j+15], b = rows
// [16(127-j),...]. One fused kv loop to b's end; a participates (sharing the
// K/V fragments) only while kv0 <= q0a+15  => per-wave work ~constant.
// XCD-chunked: XCD (bb&7) handles heads [8x,8x+8) => 4MB K/V = one L2.
// Swapped layouts: S'[kv][q] = mfma(K,Q); O'[d][q] = mfma(Vt,P).
#define SCALE_LOG2 0.18033688f   // (1/sqrt(64)) * log2(e)
#define PSTRIDE 36               // u32 stride per q-row (16B-aligned, padded)

// Online-softmax + bf16-pack for one 16-row group. sc is S'[kv][q] scaled raw.
static __device__ __forceinline__ void softmax_pack(
    f32x4 sc[4], float& m, float& l, f32x4 o[4],
    int q0, int kv0, int l15, int lhi, uint* __restrict__ P)
{
  const bool needmask = (kv0 + 63 > q0);
  float sv[4][4];
  float pm = -1e30f;
#pragma unroll
  for (int c = 0; c < 4; c++)
#pragma unroll
    for (int r = 0; r < 4; r++) {
      float xv = sc[c][r] * SCALE_LOG2;
      if (needmask) {
        int kv = kv0 + c*16 + lhi*4 + r;
        if (kv > q0 + l15) xv = -1e30f;
      }
      sv[c][r] = xv;
      pm = fmaxf(pm, xv);
    }
  pm = fmaxf(pm, __shfl_xor(pm, 16));
  pm = fmaxf(pm, __shfl_xor(pm, 32));
  float nm = fmaxf(m, pm);
  float alpha = __builtin_amdgcn_exp2f(m - nm);
  m = nm;
  float ps = 0.f;
#pragma unroll
  for (int c = 0; c < 4; c++)
#pragma unroll
    for (int r = 0; r < 4; r++) {
      float p = __builtin_amdgcn_exp2f(sv[c][r] - nm);
      sv[c][r] = p;
      ps += p;
    }
  ps += __shfl_xor(ps, 16);
  ps += __shfl_xor(ps, 32);
  l = l * alpha + ps;
#pragma unroll
  for (int n = 0; n < 4; n++)
#pragma unroll
    for (int r = 0; r < 4; r++) o[n][r] *= alpha;
  // Pack P -> bf16 pairs into wave-private LDS (relayout to PV B-fragment).
#pragma unroll
  for (int c = 0; c < 4; c++) {
    uint a, bq;
    asm("v_cvt_pk_bf16_f32 %0, %1, %2" : "=v"(a)  : "v"(sv[c][0]), "v"(sv[c][1]));
    asm("v_cvt_pk_bf16_f32 %0, %1, %2" : "=v"(bq) : "v"(sv[c][2]), "v"(sv[c][3]));
    uint2 pr; pr.x = a; pr.y = bq;
    *(uint2*)&P[l15 * PSTRIDE + c*8 + lhi*2] = pr;
  }
}

__global__ __launch_bounds__(256) void attn_k(
    const ushort* __restrict__ Q, const ushort* __restrict__ K,
    const ushort* __restrict__ V, ushort* __restrict__ AO)
{
  __shared__ uint P2[8][16 * PSTRIDE];
  const int tid = threadIdx.x;
  const int lane = tid & 63;
  const int w = tid >> 6;
  const int l15 = lane & 15, lhi = lane >> 4;
  const int bb = blockIdx.x;
  const int x = bb & 7, ii = bb >> 3;     // ii in [0,128)
  const int bh = (x << 3) | (ii >> 4);    // 64 heads, 8 per XCD
  const int j = (ii & 15) * 4 + w;        // 0..63
  const int q0a = j * 16;                 // low group
  const int q0b = (127 - j) * 16;         // high group

  const ushort* Qb = Q + (size_t)bh * T_ * D_;
  const ushort* Kb = K + (size_t)bh * T_ * D_;
  const ushort* Vb = V + (size_t)bh * D_ * T_;   // [d][t]

  // Q as B-fragment: lane holds Q[q = q0+l15][d = s*32 + lhi*8 + j]
  short8 qfa[2], qfb[2];
#pragma unroll
  for (int s = 0; s < 2; s++) {
    qfa[s] = *(const short8*)&Qb[(q0a + l15) * D_ + s * 32 + lhi * 8];
    qfb[s] = *(const short8*)&Qb[(q0b + l15) * D_ + s * 32 + lhi * 8];
  }

  f32x4 oa[4] = {}, ob[4] = {};   // O'[d][q]: d = n*16 + lhi*4 + r, q = l15
  float ma = -1e30f, la = 0.f, mb = -1e30f, lb = 0.f;

  // Prefetched K fragment for the current step.
  short8 kf[4][2];
#pragma unroll
  for (int c = 0; c < 4; c++)
#pragma unroll
    for (int s = 0; s < 2; s++)
      kf[c][s] = *(const short8*)&Kb[(size_t)(c*16 + l15) * D_ + s*32 + lhi*8];

  for (int kv0 = 0; kv0 <= q0b + 15; kv0 += 64) {
    const bool act_a = (kv0 <= q0a + 15);
    // Vt as A-fragment: lane holds Vt[d = n*16+l15][kv = kv0+ks*32+lhi*8+j]
    short8 vf[4][2];
#pragma unroll
    for (int n = 0; n < 4; n++)
#pragma unroll
      for (int ks = 0; ks < 2; ks++)
        vf[n][ks] = *(const short8*)&Vb[(size_t)(n*16 + l15) * T_ + kv0 + ks*32 + lhi*8];

    // S'[kv][q]: lane holds kv = kv0 + c*16 + lhi*4 + r for q = q0 + l15
    f32x4 sca[4], scb[4];
    __builtin_amdgcn_s_setprio(1);
#pragma unroll
    for (int c = 0; c < 4; c++) {
      f32x4 z = {};
      z = mfma16(kf[c][0], qfb[0], z);
      scb[c] = mfma16(kf[c][1], qfb[1], z);
    }
    if (act_a) {
#pragma unroll
      for (int c = 0; c < 4; c++) {
        f32x4 z = {};
        z = mfma16(kf[c][0], qfa[0], z);
        sca[c] = mfma16(kf[c][1], qfa[1], z);
      }
    }
    __builtin_amdgcn_s_setprio(0);

    // Prefetch K fragment for next step.
    {
      int kvn = kv0 + 64;
      if (kvn > T_ - 64) kvn = T_ - 64;   // clamp: values unused on last step
#pragma unroll
      for (int c = 0; c < 4; c++)
#pragma unroll
        for (int s = 0; s < 2; s++)
          kf[c][s] = *(const short8*)&Kb[(size_t)(kvn + c*16 + l15) * D_ + s*32 + lhi*8];
    }

    softmax_pack(scb, mb, lb, ob, q0b, kv0, l15, lhi, &P2[w*2][0]);
    if (act_a)
      softmax_pack(sca, ma, la, oa, q0a, kv0, l15, lhi, &P2[w*2+1][0]);

    asm volatile("s_waitcnt lgkmcnt(0)" ::: "memory");
    __builtin_amdgcn_sched_barrier(0);
    // B-fragment read: lane needs P[kv = ks*32 + lhi*8 + j][q = l15]
    short8 pfb[2], pfa[2];
#pragma unroll
    for (int ks = 0; ks < 2; ks++) {
      uint4 pw = *(const uint4*)&P2[w*2][l15 * PSTRIDE + ks*16 + lhi*4];
      __builtin_memcpy(&pfb[ks], &pw, 16);
    }
    if (act_a) {
#pragma unroll
      for (int ks = 0; ks < 2; ks++) {
        uint4 pw = *(const uint4*)&P2[w*2+1][l15 * PSTRIDE + ks*16 + lhi*4];
        __builtin_memcpy(&pfa[ks], &pw, 16);
      }
    }
    __builtin_amdgcn_s_setprio(1);
#pragma unroll
    for (int n = 0; n < 4; n++) {
      ob[n] = mfma16(vf[n][0], pfb[0], ob[n]);
      ob[n] = mfma16(vf[n][1], pfb[1], ob[n]);
    }
    if (act_a) {
#pragma unroll
      for (int n = 0; n < 4; n++) {
        oa[n] = mfma16(vf[n][0], pfa[0], oa[n]);
        oa[n] = mfma16(vf[n][1], pfa[1], oa[n]);
      }
    }
    __builtin_amdgcn_s_setprio(0);
  }

  const int b = bh >> 4, h = bh & 15;
  {
    const float invl = 1.0f / lb;
    const size_t rowb = (size_t)(b * T_ + q0b + l15) * C_ + h * 64;
#pragma unroll
    for (int n = 0; n < 4; n++) {
      ushort4 ov;
      ov.x = f2bf(ob[n][0] * invl);
      ov.y = f2bf(ob[n][1] * invl);
      ov.z = f2bf(ob[n][2] * invl);
      ov.w = f2bf(ob[n][3] * invl);
      *(ushort4*)&AO[rowb + n*16 + lhi*4] = ov;
    }
  }
  {
    const float invl = 1.0f / la;
    const size_t rowb = (size_t)(b * T_ + q0a + l15) * C_ + h * 64;
#pragma unroll
    for (int n = 0; n < 4; n++) {
      ushort4 ov;
      ov.x = f2bf(oa[n][0] * invl);
      ov.y = f2bf(oa[n][1] * invl);
      ov.z = f2bf(oa[n][2] * invl);
      ov.w = f2bf(oa[n][3] * invl);
      *(ushort4*)&AO[rowb + n*16 + lhi*4] = ov;
    }
  }
}

extern "C" void kernel_launch(void* const* d_in, const int* in_sizes, int n_in,
                              void* d_out, int out_size, void* d_ws, size_t ws_size,
                              hipStream_t stream) {
  const float* x     = (const float*)d_in[0];
  const float* w_qkv = (const float*)d_in[1];
  const float* b_qkv = (const float*)d_in[2];
  const float* w_out = (const float*)d_in[3];
  const float* b_out = (const float*)d_in[4];
  float* out = (float*)d_out;

  ushort* xb    = (ushort*)d_ws;                    // 8192*1024
  ushort* wqkvb = xb    + (size_t)M_ * C_;          // 3072*1024
  ushort* woutb = wqkvb + (size_t)3 * C_ * C_;      // 1024*1024
  ushort* q     = woutb + (size_t)C_ * C_;          // [B,H,T,D]
  ushort* kk    = q     + (size_t)M_ * C_;          // [B,H,T,D]
  ushort* vt    = kk    + (size_t)M_ * C_;          // [B,H,D,T]
  ushort* ao    = xb;                               // reuse xb (free after QKV GEMM)

  cvt_bf16<<<1024, 256, 0, stream>>>(x,     xb,    (M_ * C_) / 4);
  cvt_bf16<<<512,  256, 0, stream>>>(w_qkv, wqkvb, (3 * C_ * C_) / 4);
  cvt_bf16<<<256,  256, 0, stream>>>(w_out, woutb, (C_ * C_) / 4);

  gemm_bt<0><<<dim3(3 * C_ / 128, M_ / 128), 256, 0, stream>>>(
      xb, wqkvb, b_qkv, C_, q, kk, vt, nullptr);

  // 4 waves x (16 low + 16 high) rows = 128 rows per block -> 1024 blocks.
  attn_k<<<B_ * H_ * T_ / 128, 256, 0, stream>>>(q, kk, vt, ao);

  gemm_bt<1><<<dim3(C_ / 128, M_ / 128), 256, 0, stream>>>(
      ao, woutb, b_out, C_, nullptr, nullptr, nullptr, out);
}

// Round 6
// 319.634 us; speedup vs baseline: 1.1074x; 1.1074x over previous
//
#include <hip/hip_runtime.h>
#include <hip/hip_bf16.h>

// CausalSelfAttention: x[4,2048,1024] -> qkv proj -> 16-head causal attn -> out proj
// Pipeline: cvt(fp32->bf16) x3 -> gemm_bt<QKV> -> attn (block-coop staged) -> gemm_bt<OUT>

#define B_ 4
#define T_ 2048
#define C_ 1024
#define H_ 16
#define D_ 64
#define M_ (B_*T_)   // 8192 tokens

typedef __attribute__((ext_vector_type(8))) short short8;
typedef __attribute__((ext_vector_type(4))) float f32x4;

static __device__ __forceinline__ ushort f2bf(float f) {
  __hip_bfloat16 b = __float2bfloat16(f);
  ushort u; __builtin_memcpy(&u, &b, 2); return u;
}

static __device__ __forceinline__ void ld16(const void* g, void* l) {
  __builtin_amdgcn_global_load_lds((const __attribute__((address_space(1))) void*)g,
                                   (__attribute__((address_space(3))) void*)l, 16, 0, 0);
}

static __device__ __forceinline__ f32x4 mfma16(short8 a, short8 b, f32x4 c) {
  return __builtin_amdgcn_mfma_f32_16x16x32_bf16(a, b, c, 0, 0, 0);
}

// ---------------- fp32 -> bf16 convert ----------------
__global__ void cvt_bf16(const float* __restrict__ in, ushort* __restrict__ out, int n4) {
  int i = blockIdx.x * blockDim.x + threadIdx.x;
  int st = gridDim.x * blockDim.x;
  for (; i < n4; i += st) {
    float4 v = ((const float4*)in)[i];
    ushort4 o;
    o.x = f2bf(v.x); o.y = f2bf(v.y); o.z = f2bf(v.z); o.w = f2bf(v.w);
    ((ushort4*)out)[i] = o;
  }
}

// ---------------- C = A @ B^T + bias (both A,B K-major bf16) ----------------
// MODE 0: QKV projection -> scatter to q[B,H,T,D], k[B,H,T,D], vt[B,H,D,T] (bf16)
// MODE 1: out projection -> fp32 d_out
template<int MODE>
__global__ __launch_bounds__(256) void gemm_bt(
    const ushort* __restrict__ A, const ushort* __restrict__ Bm,
    const float* __restrict__ bias, int K,
    ushort* __restrict__ q, ushort* __restrict__ kk, ushort* __restrict__ vt,
    float* __restrict__ outF)
{
  __shared__ ushort Al[128*32];
  __shared__ ushort Bl[128*32];
  const int tid = threadIdx.x;
  const int lane = tid & 63;
  const int w = tid >> 6;
  const int wr = w >> 1, wc = w & 1;
  const int l15 = lane & 15, lhi = lane >> 4;
  const long i0 = (long)blockIdx.y * 128;
  const long j0 = (long)blockIdx.x * 128;

  f32x4 acc[4][4] = {};

  for (int k0 = 0; k0 < K; k0 += 32) {
    __syncthreads();
    {
      int c = tid;
      ld16((const char*)A  + ((i0 + (c >> 2)) * K + k0 + (c & 3) * 8) * 2, (char*)Al + c * 16);
      ld16((const char*)Bm + ((j0 + (c >> 2)) * K + k0 + (c & 3) * 8) * 2, (char*)Bl + c * 16);
      c = tid + 256;
      ld16((const char*)A  + ((i0 + (c >> 2)) * K + k0 + (c & 3) * 8) * 2, (char*)Al + c * 16);
      ld16((const char*)Bm + ((j0 + (c >> 2)) * K + k0 + (c & 3) * 8) * 2, (char*)Bl + c * 16);
    }
    __syncthreads();
    short8 af[4], bf[4];
#pragma unroll
    for (int m = 0; m < 4; m++) af[m] = *(const short8*)&Al[(wr*64 + m*16 + l15)*32 + lhi*8];
#pragma unroll
    for (int n = 0; n < 4; n++) bf[n] = *(const short8*)&Bl[(wc*64 + n*16 + l15)*32 + lhi*8];
#pragma unroll
    for (int m = 0; m < 4; m++)
#pragma unroll
      for (int n = 0; n < 4; n++)
        acc[m][n] = mfma16(af[m], bf[n], acc[m][n]);
  }

#pragma unroll
  for (int m = 0; m < 4; m++) {
#pragma unroll
    for (int n = 0; n < 4; n++) {
#pragma unroll
      for (int r = 0; r < 4; r++) {
        long i = i0 + wr*64 + m*16 + lhi*4 + r;       // token row
        int  j = (int)j0 + wc*64 + n*16 + l15;        // output feature
        float v = acc[m][n][r] + bias[j];
        if (MODE == 0) {
          int b = (int)(i >> 11), t = (int)(i & 2047);
          int sel = j >> 10, cc = j & 1023;
          int h = cc >> 6, d = cc & 63;
          long bh = (long)b * H_ + h;
          ushort bv = f2bf(v);
          if (sel == 0)      q [(bh*T_ + t)*D_ + d] = bv;
          else if (sel == 1) kk[(bh*T_ + t)*D_ + d] = bv;
          else               vt[(bh*D_ + d)*T_ + t] = bv;   // V stored transposed
        } else {
          outF[i * C_ + j] = v;
        }
      }
    }
  }
}

// ------------- causal flash attention, block-cooperative staged -------------
// 512 blocks x 512 threads (8 waves). Block bb: head = bb&63, i = bb>>6,
// J = i<4 ? i : 11-i (so co-resident bb,bb+256 have complementary length).
// Block owns two mirrored 128-row bands: low [128J,128J+127], high
// [2048-128(J+1), 2048-128J-1]; wave w takes 16 rows of each.
// Per kv-step (64 wide): K[64][64] and Vt[64][64] staged ONCE per block into
// double-buffered LDS via global_load_lds (linear dest, inverse-XOR-swizzled
// global source); fragment ds_reads apply the same XOR swizzle (involution)
// -> conflict-free. Stage of t+1 issues at step top, drains at step-end
// __syncthreads (2-phase pipeline).
// Swapped layouts: S'[kv][q] = mfma(K,Q); O'[d][q] = mfma(Vt,P).
#define SCALE_LOG2 0.18033688f   // (1/sqrt(64)) * log2(e)
#define PSTRIDE 36               // u32 stride per q-row (16B-aligned, padded)

// Online-softmax + bf16-pack for one 16-row group. sc is S'[kv][q] raw.
static __device__ __forceinline__ void softmax_pack(
    f32x4 sc[4], float& m, float& l, f32x4 o[4],
    int q0, int kv0, int l15, int lhi, uint* __restrict__ P)
{
  const bool needmask = (kv0 + 63 > q0);
  float sv[4][4];
  float pm = -1e30f;
#pragma unroll
  for (int c = 0; c < 4; c++)
#pragma unroll
    for (int r = 0; r < 4; r++) {
      float xv = sc[c][r] * SCALE_LOG2;
      if (needmask) {
        int kv = kv0 + c*16 + lhi*4 + r;
        if (kv > q0 + l15) xv = -1e30f;
      }
      sv[c][r] = xv;
      pm = fmaxf(pm, xv);
    }
  pm = fmaxf(pm, __shfl_xor(pm, 16));
  pm = fmaxf(pm, __shfl_xor(pm, 32));
  float nm = fmaxf(m, pm);
  float alpha = __builtin_amdgcn_exp2f(m - nm);
  m = nm;
  float ps = 0.f;
#pragma unroll
  for (int c = 0; c < 4; c++)
#pragma unroll
    for (int r = 0; r < 4; r++) {
      float p = __builtin_amdgcn_exp2f(sv[c][r] - nm);
      sv[c][r] = p;
      ps += p;
    }
  ps += __shfl_xor(ps, 16);
  ps += __shfl_xor(ps, 32);
  l = l * alpha + ps;
#pragma unroll
  for (int n = 0; n < 4; n++)
#pragma unroll
    for (int r = 0; r < 4; r++) o[n][r] *= alpha;
#pragma unroll
  for (int c = 0; c < 4; c++) {
    uint a, bq;
    asm("v_cvt_pk_bf16_f32 %0, %1, %2" : "=v"(a)  : "v"(sv[c][0]), "v"(sv[c][1]));
    asm("v_cvt_pk_bf16_f32 %0, %1, %2" : "=v"(bq) : "v"(sv[c][2]), "v"(sv[c][3]));
    uint2 pr; pr.x = a; pr.y = bq;
    *(uint2*)&P[l15 * PSTRIDE + c*8 + lhi*2] = pr;
  }
}

__global__ __launch_bounds__(512, 4) void attn_k(
    const ushort* __restrict__ Q, const ushort* __restrict__ K,
    const ushort* __restrict__ V, ushort* __restrict__ AO)
{
  __shared__ ushort Kt[2][64*64];
  __shared__ ushort Vt[2][64*64];
  __shared__ uint P2[16][16 * PSTRIDE];
  const int tid = threadIdx.x;
  const int lane = tid & 63;
  const int w = tid >> 6;
  const int l15 = lane & 15, lhi = lane >> 4;
  const int bb = blockIdx.x;
  const int head = bb & 63;                 // 8 heads per XCD (bb%8 = head%8)
  const int i = bb >> 6;                    // 0..7
  const int J = (i < 4) ? i : 11 - i;       // complementary pairing b, b+256
  const int nst = 32 - 2 * J;               // kv steps (uniform per block)
  const int q0a = 128 * J + 16 * w;                 // low band rows
  const int q0b = 2048 - 128 * (J + 1) + 16 * w;    // high band rows

  const ushort* Qb = Q + (size_t)head * T_ * D_;
  const ushort* Kb = K + (size_t)head * T_ * D_;
  const ushort* Vb = V + (size_t)head * D_ * T_;   // [d][t]

  // Stage one kv-step: K tile [64][64] + Vt tile [64][64], 1 slot per thread
  // per tile. LDS dest linear; global source unit pre-XORed so that a
  // swizzled read (unit ^ (row&7)) returns the natural layout.
  auto STAGE = [&](int buf, int kv0s) {
    const int srow = tid >> 3, su = tid & 7, gu = su ^ (srow & 7);
    ld16((const char*)Kb + ((size_t)(kv0s + srow) * D_ + gu * 8) * 2,
         (char*)&Kt[buf][0] + tid * 16);
    ld16((const char*)Vb + ((size_t)srow * T_ + kv0s + gu * 8) * 2,
         (char*)&Vt[buf][0] + tid * 16);
  };

  // Q as B-fragment: lane holds Q[q = q0+l15][d = s*32 + lhi*8 + j]
  short8 qfa[2], qfb[2];
#pragma unroll
  for (int s = 0; s < 2; s++) {
    qfa[s] = *(const short8*)&Qb[(q0a + l15) * D_ + s * 32 + lhi * 8];
    qfb[s] = *(const short8*)&Qb[(q0b + l15) * D_ + s * 32 + lhi * 8];
  }

  f32x4 oa[4] = {}, ob[4] = {};   // O'[d][q]: d = n*16 + lhi*4 + r, q = l15
  float ma = -1e30f, la = 0.f, mb = -1e30f, lb = 0.f;

  STAGE(0, 0);
  __syncthreads();                 // compiler drains vmcnt before barrier
  int cur = 0;

  for (int t = 0; t < nst; t++) {
    const int kv0 = t * 64;
    if (t + 1 < nst) STAGE(cur ^ 1, kv0 + 64);   // prefetch next tile
    const bool act_a = (kv0 <= q0a + 15);
    const bool act_b = (kv0 <= q0b + 15);

    // QK^T per k-slice (kf liveness = 4 fragments)
    f32x4 sca[4] = {}, scb[4] = {};
#pragma unroll
    for (int s = 0; s < 2; s++) {
      short8 kfs[4];
#pragma unroll
      for (int c = 0; c < 4; c++) {
        const int r = c*16 + l15, u = s*4 + lhi;
        kfs[c] = *(const short8*)&Kt[cur][r*64 + ((u ^ (r & 7)) << 3)];
      }
      __builtin_amdgcn_s_setprio(1);
      if (act_b) {
#pragma unroll
        for (int c = 0; c < 4; c++) scb[c] = mfma16(kfs[c], qfb[s], scb[c]);
      }
      if (act_a) {
#pragma unroll
        for (int c = 0; c < 4; c++) sca[c] = mfma16(kfs[c], qfa[s], sca[c]);
      }
      __builtin_amdgcn_s_setprio(0);
    }

    // V fragments issued early: latency hides under softmax.
    short8 vfr[4][2];
#pragma unroll
    for (int n = 0; n < 4; n++)
#pragma unroll
      for (int ks = 0; ks < 2; ks++) {
        const int r = n*16 + l15, u = ks*4 + lhi;
        vfr[n][ks] = *(const short8*)&Vt[cur][r*64 + ((u ^ (r & 7)) << 3)];
      }

    if (act_b) softmax_pack(scb, mb, lb, ob, q0b, kv0, l15, lhi, &P2[w*2][0]);
    if (act_a) softmax_pack(sca, ma, la, oa, q0a, kv0, l15, lhi, &P2[w*2+1][0]);

    asm volatile("s_waitcnt lgkmcnt(0)" ::: "memory");
    __builtin_amdgcn_sched_barrier(0);
    // B-fragment read: lane needs P[kv = ks*32 + lhi*8 + j][q = l15]
    short8 pfb[2], pfa[2];
    if (act_b) {
#pragma unroll
      for (int ks = 0; ks < 2; ks++) {
        uint4 pw = *(const uint4*)&P2[w*2][l15 * PSTRIDE + ks*16 + lhi*4];
        __builtin_memcpy(&pfb[ks], &pw, 16);
      }
    }
    if (act_a) {
#pragma unroll
      for (int ks = 0; ks < 2; ks++) {
        uint4 pw = *(const uint4*)&P2[w*2+1][l15 * PSTRIDE + ks*16 + lhi*4];
        __builtin_memcpy(&pfa[ks], &pw, 16);
      }
    }
    __builtin_amdgcn_s_setprio(1);
    if (act_b) {
#pragma unroll
      for (int n = 0; n < 4; n++) {
        ob[n] = mfma16(vfr[n][0], pfb[0], ob[n]);
        ob[n] = mfma16(vfr[n][1], pfb[1], ob[n]);
      }
    }
    if (act_a) {
#pragma unroll
      for (int n = 0; n < 4; n++) {
        oa[n] = mfma16(vfr[n][0], pfa[0], oa[n]);
        oa[n] = mfma16(vfr[n][1], pfa[1], oa[n]);
      }
    }
    __builtin_amdgcn_s_setprio(0);

    __syncthreads();               // next tile staged; this tile free
    cur ^= 1;
  }

  const int b = head >> 4, h = head & 15;
  {
    const float invl = 1.0f / lb;
    const size_t rowb = (size_t)(b * T_ + q0b + l15) * C_ + h * 64;
#pragma unroll
    for (int n = 0; n < 4; n++) {
      ushort4 ov;
      ov.x = f2bf(ob[n][0] * invl);
      ov.y = f2bf(ob[n][1] * invl);
      ov.z = f2bf(ob[n][2] * invl);
      ov.w = f2bf(ob[n][3] * invl);
      *(ushort4*)&AO[rowb + n*16 + lhi*4] = ov;
    }
  }
  {
    const float invl = 1.0f / la;
    const size_t rowb = (size_t)(b * T_ + q0a + l15) * C_ + h * 64;
#pragma unroll
    for (int n = 0; n < 4; n++) {
      ushort4 ov;
      ov.x = f2bf(oa[n][0] * invl);
      ov.y = f2bf(oa[n][1] * invl);
      ov.z = f2bf(oa[n][2] * invl);
      ov.w = f2bf(oa[n][3] * invl);
      *(ushort4*)&AO[rowb + n*16 + lhi*4] = ov;
    }
  }
}

extern "C" void kernel_launch(void* const* d_in, const int* in_sizes, int n_in,
                              void* d_out, int out_size, void* d_ws, size_t ws_size,
                              hipStream_t stream) {
  const float* x     = (const float*)d_in[0];
  const float* w_qkv = (const float*)d_in[1];
  const float* b_qkv = (const float*)d_in[2];
  const float* w_out = (const float*)d_in[3];
  const float* b_out = (const float*)d_in[4];
  float* out = (float*)d_out;

  ushort* xb    = (ushort*)d_ws;                    // 8192*1024
  ushort* wqkvb = xb    + (size_t)M_ * C_;          // 3072*1024
  ushort* woutb = wqkvb + (size_t)3 * C_ * C_;      // 1024*1024
  ushort* q     = woutb + (size_t)C_ * C_;          // [B,H,T,D]
  ushort* kk    = q     + (size_t)M_ * C_;          // [B,H,T,D]
  ushort* vt    = kk    + (size_t)M_ * C_;          // [B,H,D,T]
  ushort* ao    = xb;                               // reuse xb (free after QKV GEMM)

  cvt_bf16<<<1024, 256, 0, stream>>>(x,     xb,    (M_ * C_) / 4);
  cvt_bf16<<<512,  256, 0, stream>>>(w_qkv, wqkvb, (3 * C_ * C_) / 4);
  cvt_bf16<<<256,  256, 0, stream>>>(w_out, woutb, (C_ * C_) / 4);

  gemm_bt<0><<<dim3(3 * C_ / 128, M_ / 128), 256, 0, stream>>>(
      xb, wqkvb, b_qkv, C_, q, kk, vt, nullptr);

  // 8 waves x (16 low + 16 high) rows = 256 rows per block -> 512 blocks.
  attn_k<<<B_ * H_ * T_ / 256, 512, 0, stream>>>(q, kk, vt, ao);

  gemm_bt<1><<<dim3(C_ / 128, M_ / 128), 256, 0, stream>>>(
      ao, woutb, b_out, C_, nullptr, nullptr, nullptr, out);
}